// Round 1
// baseline (614.003 us; speedup 1.0000x reference)
//
#include <hip/hip_runtime.h>

// Problem constants: B=8, T=256, U=64, D=640, V=1024
//   enc  [8,256,640] f32, pred [8,64,640] f32, W [1024,1280] f32, bias [1024] f32
//   out  = [131072,1024] f32 joint ++ [8] source_lengths ++ [8] target_lengths
//
// Factorization: relu(concat(e,p)) @ W^T = relu(e)@W[:, :640]^T + relu(p)@W[:, 640:]^T
//   E[bt, v] = sum_d relu(enc[bt,d]) * W[v,d] + bias[v]     (2048 x 1024)
//   P[bu, v] = sum_d relu(pred[bu,d]) * W[v,640+d]          (512  x 1024)
//   out[bt*64+u, v] = E[bt,v] + P[(bt>>8)*64+u, v]

#define BM 64
#define BN 64
#define BK 16
#define TPAD 4

__global__ __launch_bounds__(256) void gemm_relu_kernel(
    const float* __restrict__ enc,   // [2048, 640]
    const float* __restrict__ pred,  // [512, 640]
    const float* __restrict__ W,     // [1024, 1280]
    const float* __restrict__ bias,  // [1024]
    float* __restrict__ E,           // [2048, 1024]
    float* __restrict__ P)           // [512, 1024]
{
    __shared__ float As[BK][BM + TPAD];
    __shared__ float Bs[BK][BN + TPAD];

    const int tid  = threadIdx.x;
    const int row0 = blockIdx.y * BM;   // 0..2496; tiles never straddle E/P (2048 % 64 == 0)
    const int col0 = blockIdx.x * BN;

    const bool isE = row0 < 2048;
    const float* A = isE ? (enc + (size_t)row0 * 640)
                         : (pred + (size_t)(row0 - 2048) * 640);
    float* outp    = isE ? (E + (size_t)row0 * 1024)
                         : (P + (size_t)(row0 - 2048) * 1024);
    const int woff = isE ? 0 : 640;

    // loader mapping: 256 threads, each loads one float4 of A-tile and W-tile
    const int lm = tid >> 2;          // 0..63 (tile row for A, vocab row for W)
    const int lk = (tid & 3) * 4;     // 0,4,8,12 within K-tile

    // compute mapping: 16x16 threads, 4x4 micro-tile each
    const int tx = tid & 15;
    const int ty = tid >> 4;

    float acc[4][4];
    #pragma unroll
    for (int i = 0; i < 4; ++i)
        #pragma unroll
        for (int j = 0; j < 4; ++j) acc[i][j] = 0.f;

    for (int k0 = 0; k0 < 640; k0 += BK) {
        float4 a4 = *(const float4*)(A + (size_t)lm * 640 + k0 + lk);
        float4 b4 = *(const float4*)(W + (size_t)(col0 + lm) * 1280 + woff + k0 + lk);
        As[lk + 0][lm] = fmaxf(a4.x, 0.f);
        As[lk + 1][lm] = fmaxf(a4.y, 0.f);
        As[lk + 2][lm] = fmaxf(a4.z, 0.f);
        As[lk + 3][lm] = fmaxf(a4.w, 0.f);
        Bs[lk + 0][lm] = b4.x;
        Bs[lk + 1][lm] = b4.y;
        Bs[lk + 2][lm] = b4.z;
        Bs[lk + 3][lm] = b4.w;
        __syncthreads();

        #pragma unroll
        for (int k = 0; k < BK; ++k) {
            float4 av = *(const float4*)&As[k][ty * 4];
            float4 bv = *(const float4*)&Bs[k][tx * 4];
            float ar[4] = {av.x, av.y, av.z, av.w};
            float br[4] = {bv.x, bv.y, bv.z, bv.w};
            #pragma unroll
            for (int i = 0; i < 4; ++i)
                #pragma unroll
                for (int j = 0; j < 4; ++j)
                    acc[i][j] = fmaf(ar[i], br[j], acc[i][j]);
        }
        __syncthreads();
    }

    float4 bb = make_float4(0.f, 0.f, 0.f, 0.f);
    if (isE) bb = *(const float4*)(bias + col0 + tx * 4);

    #pragma unroll
    for (int i = 0; i < 4; ++i) {
        float4 o;
        o.x = acc[i][0] + bb.x;
        o.y = acc[i][1] + bb.y;
        o.z = acc[i][2] + bb.z;
        o.w = acc[i][3] + bb.w;
        *(float4*)(outp + (size_t)(ty * 4 + i) * 1024 + col0 + tx * 4) = o;
    }
}

// One block per (b,t) row of E; loops over the 64 u rows of P for that batch.
// E-row (4 KB) held in registers; P rows (256 KB per batch) are L2-resident.
__global__ __launch_bounds__(256) void bcast_add_kernel(
    const float* __restrict__ E,   // [2048, 1024] (bias already folded)
    const float* __restrict__ P,   // [512, 1024]
    float* __restrict__ out)       // [131072, 1024]
{
    const int bt  = blockIdx.x;      // b*256 + t
    const int b   = bt >> 8;
    const int tid = threadIdx.x;     // 256 threads x float4 = 1024 cols

    const float4 e4 = ((const float4*)(E + (size_t)bt * 1024))[tid];
    const float4* Pb = (const float4*)(P + (size_t)b * 64 * 1024);
    float4* ob = (float4*)(out + (size_t)bt * 64 * 1024);

    #pragma unroll 4
    for (int u = 0; u < 64; ++u) {
        float4 p4 = Pb[u * 256 + tid];
        float4 o;
        o.x = e4.x + p4.x;
        o.y = e4.y + p4.y;
        o.z = e4.z + p4.z;
        o.w = e4.w + p4.w;
        ob[u * 256 + tid] = o;
    }
}

__global__ void lengths_kernel(const int* __restrict__ sl,
                               const int* __restrict__ tl,
                               float* __restrict__ out_tail)
{
    const int i = threadIdx.x;
    if (i < 8) {
        out_tail[i]     = (float)sl[i];
        out_tail[8 + i] = (float)tl[i];
    }
}

extern "C" void kernel_launch(void* const* d_in, const int* in_sizes, int n_in,
                              void* d_out, int out_size, void* d_ws, size_t ws_size,
                              hipStream_t stream) {
    const float* enc  = (const float*)d_in[0];   // [8,256,640]
    const int*   sl   = (const int*)d_in[1];     // [8]
    const float* pred = (const float*)d_in[2];   // [8,64,640]
    const int*   tl   = (const int*)d_in[3];     // [8]
    const float* W    = (const float*)d_in[4];   // [1024,1280]
    const float* bias = (const float*)d_in[5];   // [1024]

    float* out = (float*)d_out;
    float* E = (float*)d_ws;                     // 2048*1024 f32 = 8 MB
    float* P = E + 2048 * 1024;                  // 512*1024 f32  = 2 MB

    dim3 g1(1024 / BN, 2560 / BM);               // (16, 40)
    gemm_relu_kernel<<<g1, 256, 0, stream>>>(enc, pred, W, bias, E, P);

    bcast_add_kernel<<<2048, 256, 0, stream>>>(E, P, out);

    lengths_kernel<<<1, 64, 0, stream>>>(sl, tl, out + (size_t)131072 * 1024);
}